// Round 1
// baseline (2622.777 us; speedup 1.0000x reference)
//
#include <hip/hip_runtime.h>
#include <hip/hip_bf16.h>

#define NN 1024
#define EE 4096
#define CC 32     // channels C
#define SD 16     // SUM_DIM
#define FQ 44     // FREQ_SUM
#define MIDC 32   // MLP mid
#define EB 8      // edges per workgroup

// ---------------- K0: transpose w3 (32, 45056) -> w3t[f][m][o][c] ----------------
__global__ __launch_bounds__(256) void k_w3t(const float* __restrict__ w3,
                                             float* __restrict__ w3t) {
    int idx = blockIdx.x * 256 + threadIdx.x;   // over 32*45056 = 1441792
    if (idx >= MIDC * 45056) return;
    int m = idx / 45056;
    int j = idx - m * 45056;         // j = o*1408 + c*44 + f
    int o = j / 1408;
    int r = j - o * 1408;
    int c = r / 44;
    int f = r - c * 44;
    w3t[((f * MIDC + m) * CC + o) * CC + c] = w3[idx];
}

// ---------------- K1: h = relu(relu(inv@w1+b1)@w2+b2), deg counts ----------------
__global__ __launch_bounds__(256) void k_h(const float* __restrict__ ef,
                                           const float* __restrict__ w1,
                                           const float* __restrict__ b1,
                                           const float* __restrict__ w2,
                                           const float* __restrict__ b2,
                                           const int* __restrict__ dst,
                                           float* __restrict__ h,
                                           int* __restrict__ deg) {
    int e = blockIdx.x * 256 + threadIdx.x;
    if (e >= EE) return;
    float i0 = ef[e * 2 + 0], i1 = ef[e * 2 + 1];
    float h1[MIDC];
#pragma unroll
    for (int j = 0; j < MIDC; j++) {
        float v = i0 * w1[j] + i1 * w1[MIDC + j] + b1[j];
        h1[j] = v > 0.f ? v : 0.f;
    }
    for (int j = 0; j < MIDC; j++) {
        float v = b2[j];
#pragma unroll
        for (int m = 0; m < MIDC; m++) v += h1[m] * w2[m * MIDC + j];
        v = v > 0.f ? v : 0.f;
        h[e * MIDC + j] = v;
    }
    atomicAdd(&deg[dst[e]], 1);
}

// ---------------- K2: main fused kernel ----------------
// One workgroup = EB edges. Loop over f. Per thread: (e = t>>5, o = t&31),
// accumulates out_fused[e][o][s] (s in [0,16)) in registers.
__global__ __launch_bounds__(256) void k_main(
    const float* __restrict__ nf0, const float* __restrict__ nf1,
    const float* __restrict__ nf2, const float* __restrict__ nf3,
    const float* __restrict__ basis, const int* __restrict__ src,
    const int* __restrict__ dst, const float* __restrict__ h,
    const float* __restrict__ w3t, float* __restrict__ out) {
    __shared__ float h_lds[EB][MIDC];          // 1 KB
    __shared__ float feats_lds[EB][CC][SD];    // 16 KB
    __shared__ float basis_lds[EB][SD][SD];    // 8 KB  [e][i][s] for current f
    __shared__ float U_lds[EB][SD][CC];        // 16 KB [e][s][c]
    __shared__ int dst_lds[EB];

    int t = threadIdx.x;
    int eb = blockIdx.x * EB;
    int e = t >> 5;
    int oc = t & 31;   // serves as both o (phase C) and c (phases feats/B)

    h_lds[e][oc] = h[(eb + e) * MIDC + oc];
    if (t < EB) dst_lds[t] = dst[eb + t];

    // gather feats[e][c][0:16] from the 4 degree arrays (concat on last axis)
    {
        int sn = src[eb + e];
        int c = oc;
        feats_lds[e][c][0] = nf0[sn * CC + c];
#pragma unroll
        for (int j = 0; j < 3; j++) feats_lds[e][c][1 + j] = nf1[(sn * CC + c) * 3 + j];
#pragma unroll
        for (int j = 0; j < 5; j++) feats_lds[e][c][4 + j] = nf2[(sn * CC + c) * 5 + j];
#pragma unroll
        for (int j = 0; j < 7; j++) feats_lds[e][c][9 + j] = nf3[(sn * CC + c) * 7 + j];
    }
    __syncthreads();

    // per-thread copy of feats row (mapping (e,c) identical to the gather above)
    float fr[SD];
#pragma unroll
    for (int i = 0; i < SD; i++) fr[i] = feats_lds[e][oc][i];

    float oacc[SD];
#pragma unroll
    for (int s = 0; s < SD; s++) oacc[s] = 0.f;

    for (int f = 0; f < FQ; f++) {
        // ---- phase A: stage basis[:, :, f, :] for the block (2048 floats) ----
        {
            int q = t * 8;
            int be = q >> 8;
            int bi = (q >> 4) & 15;
            int bs = q & 15;   // 0 or 8
            const float4* gp = reinterpret_cast<const float4*>(
                &basis[(((size_t)(eb + be) * SD + bi) * FQ + f) * SD + bs]);
            float4 v0 = gp[0];
            float4 v1 = gp[1];
            float4* lp = reinterpret_cast<float4*>(&basis_lds[be][bi][bs]);
            lp[0] = v0;
            lp[1] = v1;
        }
        __syncthreads();

        // ---- phase B: U[e][s][c] = sum_i feats[e][c][i] * basis[e][i][f][s] ----
        {
            int c = oc;
#pragma unroll
            for (int s = 0; s < SD; s++) {
                float acc = 0.f;
#pragma unroll
                for (int i = 0; i < SD; i++) acc += fr[i] * basis_lds[e][i][s];
                U_lds[e][s][c] = acc;
            }
        }
        __syncthreads();

        // ---- phase C: rad[c] = sum_m h[e][m]*w3t[f][m][o][c]; oacc += rad @ U ----
        {
            int o = oc;
            float rad[CC];
#pragma unroll
            for (int c = 0; c < CC; c++) rad[c] = 0.f;
            for (int m = 0; m < MIDC; m++) {
                float hm = h_lds[e][m];
                const float4* wp4 = reinterpret_cast<const float4*>(
                    &w3t[((size_t)(f * MIDC + m) * CC + o) * CC]);
#pragma unroll
                for (int c4 = 0; c4 < 8; c4++) {
                    float4 w = wp4[c4];
                    rad[c4 * 4 + 0] += hm * w.x;
                    rad[c4 * 4 + 1] += hm * w.y;
                    rad[c4 * 4 + 2] += hm * w.z;
                    rad[c4 * 4 + 3] += hm * w.w;
                }
            }
#pragma unroll
            for (int s = 0; s < SD; s++) {
                const float4* up = reinterpret_cast<const float4*>(&U_lds[e][s][0]);
                float a = 0.f;
#pragma unroll
                for (int c4 = 0; c4 < 8; c4++) {
                    float4 u = up[c4];
                    a += rad[c4 * 4 + 0] * u.x + rad[c4 * 4 + 1] * u.y +
                         rad[c4 * 4 + 2] * u.z + rad[c4 * 4 + 3] * u.w;
                }
                oacc[s] += a;
            }
        }
        __syncthreads();
    }

    // ---- scatter into output (segment sum over dst) ----
    {
        int d = dst_lds[e];
        float* op = &out[((size_t)d * CC + oc) * SD];
#pragma unroll
        for (int s = 0; s < SD; s++) atomicAdd(&op[s], oacc[s]);
    }
}

// ---------------- K3: self-interaction  out[n][o][s] += deg[n]*sum_c ks_d[o][c]*nf_d[n][c][s-off] ----
__global__ __launch_bounds__(256) void k_self(
    const float* __restrict__ nf0, const float* __restrict__ nf1,
    const float* __restrict__ nf2, const float* __restrict__ nf3,
    const float* __restrict__ ks0, const float* __restrict__ ks1,
    const float* __restrict__ ks2, const float* __restrict__ ks3,
    const int* __restrict__ deg, float* __restrict__ out) {
    int idx = blockIdx.x * 256 + threadIdx.x;   // over N*32*16 = 524288
    if (idx >= NN * CC * SD) return;
    int n = idx >> 9;
    int rem = idx & 511;
    int o = rem >> 4;
    int s = rem & 15;
    const float* nf;
    const float* ks;
    int dim, off;
    if (s < 1) { nf = nf0; ks = ks0; dim = 1; off = 0; }
    else if (s < 4) { nf = nf1; ks = ks1; dim = 3; off = 1; }
    else if (s < 9) { nf = nf2; ks = ks2; dim = 5; off = 4; }
    else { nf = nf3; ks = ks3; dim = 7; off = 9; }
    int j = s - off;
    float acc = 0.f;
#pragma unroll
    for (int c = 0; c < CC; c++) acc += ks[o * CC + c] * nf[(n * CC + c) * dim + j];
    out[idx] += (float)deg[n] * acc;
}

extern "C" void kernel_launch(void* const* d_in, const int* in_sizes, int n_in,
                              void* d_out, int out_size, void* d_ws, size_t ws_size,
                              hipStream_t stream) {
    const float* nf0 = (const float*)d_in[0];
    const float* nf1 = (const float*)d_in[1];
    const float* nf2 = (const float*)d_in[2];
    const float* nf3 = (const float*)d_in[3];
    const float* ef = (const float*)d_in[4];
    const float* basis = (const float*)d_in[5];
    const int* src = (const int*)d_in[6];
    const int* dst = (const int*)d_in[7];
    const float* w1 = (const float*)d_in[8];
    const float* b1 = (const float*)d_in[9];
    const float* w2 = (const float*)d_in[10];
    const float* b2 = (const float*)d_in[11];
    const float* w3 = (const float*)d_in[12];
    const float* ks0 = (const float*)d_in[13];
    const float* ks1 = (const float*)d_in[14];
    const float* ks2 = (const float*)d_in[15];
    const float* ks3 = (const float*)d_in[16];
    float* out = (float*)d_out;

    // workspace layout
    float* h = (float*)d_ws;                                  // E*32 floats = 512 KB
    int* deg = (int*)((char*)d_ws + EE * MIDC * 4);           // N ints = 4 KB
    float* w3t = (float*)((char*)d_ws + EE * MIDC * 4 + 4096);// 44*32*32*32 floats = 5.77 MB

    hipMemsetAsync(d_out, 0, (size_t)out_size * sizeof(float), stream);
    hipMemsetAsync(deg, 0, NN * sizeof(int), stream);

    k_w3t<<<(MIDC * 45056) / 256, 256, 0, stream>>>(w3, w3t);
    k_h<<<EE / 256, 256, 0, stream>>>(ef, w1, b1, w2, b2, dst, h, deg);
    k_main<<<EE / EB, 256, 0, stream>>>(nf0, nf1, nf2, nf3, basis, src, dst, h, w3t, out);
    k_self<<<(NN * CC * SD) / 256, 256, 0, stream>>>(nf0, nf1, nf2, nf3, ks0, ks1,
                                                     ks2, ks3, deg, out);
}

// Round 2
// 130.949 us; speedup vs baseline: 20.0290x; 20.0290x over previous
//
#include <hip/hip_runtime.h>
#include <hip/hip_bf16.h>

#define NN 1024
#define EE 4096
#define CC 32     // channels C
#define SD 16     // SUM_DIM
#define FQ 44     // FREQ_SUM
#define MIDC 32   // MLP mid
#define EB 16     // edges per workgroup

typedef short s16x4 __attribute__((ext_vector_type(4)));
typedef short s16x8 __attribute__((ext_vector_type(8)));
typedef float fx4 __attribute__((ext_vector_type(4)));

__device__ __forceinline__ unsigned short f2b(float x) {
    __hip_bfloat16 b = __float2bfloat16(x);
    return *reinterpret_cast<unsigned short*>(&b);
}

// ---------------- K0: w3 (m, o*1408 + c*44 + f) -> w3t2[f][o][c][m] bf16 ----------------
__global__ __launch_bounds__(256) void k_w3t2(const float* __restrict__ w3,
                                              unsigned short* __restrict__ w3t2) {
    int tid = blockIdx.x * 256 + threadIdx.x;   // 32768 threads
    int m = tid & 31;
    int o = (tid >> 5) & 31;
    int c = tid >> 10;
    const float* rp = &w3[(size_t)m * 45056 + o * 1408 + c * 44];
    float v[44];
#pragma unroll
    for (int q = 0; q < 11; q++) {
        float4 t4 = *(const float4*)(rp + q * 4);
        v[q * 4 + 0] = t4.x; v[q * 4 + 1] = t4.y;
        v[q * 4 + 2] = t4.z; v[q * 4 + 3] = t4.w;
    }
#pragma unroll
    for (int f = 0; f < FQ; f++) {
        // m-contiguous writes: consecutive lanes (m) -> contiguous 2B
        w3t2[(((size_t)f * CC + o) * CC + c) * CC + m] = f2b(v[f]);
    }
}

// ---------------- K1: h2 = bf16(relu(relu(inv@w1+b1)@w2+b2)), deg counts ----------------
__global__ __launch_bounds__(256) void k_h(const float* __restrict__ ef,
                                           const float* __restrict__ w1,
                                           const float* __restrict__ b1,
                                           const float* __restrict__ w2,
                                           const float* __restrict__ b2,
                                           const int* __restrict__ dst,
                                           unsigned short* __restrict__ h2,
                                           int* __restrict__ deg) {
    int e = blockIdx.x * 256 + threadIdx.x;
    if (e >= EE) return;
    float i0 = ef[e * 2 + 0], i1 = ef[e * 2 + 1];
    float h1[MIDC];
#pragma unroll
    for (int j = 0; j < MIDC; j++) {
        float v = i0 * w1[j] + i1 * w1[MIDC + j] + b1[j];
        h1[j] = v > 0.f ? v : 0.f;
    }
    for (int j = 0; j < MIDC; j++) {
        float v = b2[j];
#pragma unroll
        for (int m = 0; m < MIDC; m++) v += h1[m] * w2[m * MIDC + j];
        v = v > 0.f ? v : 0.f;
        h2[e * MIDC + j] = f2b(v);
    }
    atomicAdd(&deg[dst[e]], 1);
}

// ---------------- K2: fused MFMA main kernel ----------------
// grid = 512: blockIdx -> (e-group of 16, f-half of 22). 512 threads = 8 waves.
__global__ __launch_bounds__(512, 4) void k_main(
    const float* __restrict__ nf0, const float* __restrict__ nf1,
    const float* __restrict__ nf2, const float* __restrict__ nf3,
    const float* __restrict__ basis, const int* __restrict__ src,
    const int* __restrict__ dst, const unsigned short* __restrict__ h2,
    const unsigned short* __restrict__ w3t2, float* __restrict__ out) {
    __shared__ __align__(16) unsigned short rad_lds[EB * CC * CC];   // 32768 B, swizzled
    __shared__ __align__(16) unsigned short U_lds[EB * SD * 40];     // 20480 B
    __shared__ __align__(16) unsigned short basT[EB * SD * 40];      // 20480 B

    int t = threadIdx.x;
    int wave = t >> 6;
    int l = t & 63;
    int l15 = l & 15;
    int kg = l >> 4;            // k-group 0..3
    int eg = blockIdx.x >> 1;
    int fhalf = blockIdx.x & 1;
    int eb = eg * EB;

    // ---- setup: gather feats (f32) into fstage (aliases rad_lds: 8192 floats) ----
    float* fstage = (float*)rad_lds;
    {
        int e = t >> 5, c = t & 31;
        int sn = src[eb + e];
        float* row = &fstage[(e * CC + c) * SD];
        row[0] = nf0[sn * CC + c];
#pragma unroll
        for (int j = 0; j < 3; j++) row[1 + j] = nf1[(sn * CC + c) * 3 + j];
#pragma unroll
        for (int j = 0; j < 5; j++) row[4 + j] = nf2[(sn * CC + c) * 5 + j];
#pragma unroll
        for (int j = 0; j < 7; j++) row[9 + j] = nf3[(sn * CC + c) * 7 + j];
    }
    // h2 fragment (B of rad mfma): lane: e = l15, k = m in [kg*8, kg*8+8)
    s16x8 h2frag = *(const s16x8*)(h2 + ((size_t)(eb + l15) * MIDC + (kg << 3)));
    __syncthreads();

    // ---- feats fragments (A of U mfma) into registers; zero basT ----
    s16x8 feats[2][2];
#pragma unroll
    for (int ei = 0; ei < 2; ei++) {
        int e = wave * 2 + ei;
#pragma unroll
        for (int ch = 0; ch < 2; ch++) {
            int cc = ch * 16 + l15;
            s16x8 fr = {};
            if (kg < 2) {
                const float4* fp4 = (const float4*)&fstage[(e * CC + cc) * SD + kg * 8];
                float4 a = fp4[0], b = fp4[1];
                fr[0] = (short)f2b(a.x); fr[1] = (short)f2b(a.y);
                fr[2] = (short)f2b(a.z); fr[3] = (short)f2b(a.w);
                fr[4] = (short)f2b(b.x); fr[5] = (short)f2b(b.y);
                fr[6] = (short)f2b(b.z); fr[7] = (short)f2b(b.w);
            }
            feats[ei][ch] = fr;
        }
    }
    for (int k = t; k < EB * SD * 40; k += 512) basT[k] = 0;
    __syncthreads();

    fx4 acc[4];
#pragma unroll
    for (int q = 0; q < 4; q++) acc[q] = (fx4){0.f, 0.f, 0.f, 0.f};
    fx4 zz = (fx4){0.f, 0.f, 0.f, 0.f};

    for (int fi = 0; fi < 22; fi++) {
        int f = fhalf * 22 + fi;

        // ---- P1a: stage basis[:, :, f, :] -> basT[e][s][i] bf16 (i<16; pad stays 0) ----
        {
            int e = t >> 5, i = (t >> 1) & 15, sh = t & 1;
            const float* gp = &basis[(((size_t)(eb + e) * SD + i) * FQ + f) * SD + sh * 8];
            float4 v0 = *(const float4*)gp;
            float4 v1 = *(const float4*)(gp + 4);
            float vs[8] = {v0.x, v0.y, v0.z, v0.w, v1.x, v1.y, v1.z, v1.w};
#pragma unroll
            for (int j = 0; j < 8; j++) {
                int s = sh * 8 + j;
                int byte = (e * SD + s) * 80 + i * 2;
                byte ^= ((((e & 1) << 1) | (s >> 3)) << 4);
                *(unsigned short*)((char*)basT + byte) = f2b(vs[j]);
            }
        }

        // ---- P1b: rad tiles: C[(o,c)-16][e-16] = w3t2[f] @ h2 ----
#pragma unroll
        for (int j = 0; j < 8; j++) {
            int o = wave * 4 + (j >> 1);
            int ch = j & 1;
            const s16x8* ap = (const s16x8*)(w3t2 +
                ((((size_t)f * CC + o) * CC + ch * 16 + l15) * CC + (kg << 3)));
            s16x8 af = *ap;
            fx4 cf = __builtin_amdgcn_mfma_f32_16x16x32_bf16(af, h2frag, zz, 0, 0, 0);
            // lane: e_w = l15; c = ch*16 + kg*4 + r (4 consecutive) -> b64 write
            int c_w = ch * 16 + (kg << 2);
            int byte = l15 * 2048 + o * 64 + c_w * 2;
            byte ^= (((l15 ^ o) & 7) << 4);
            s16x4 pk;
            pk[0] = (short)f2b(cf[0]); pk[1] = (short)f2b(cf[1]);
            pk[2] = (short)f2b(cf[2]); pk[3] = (short)f2b(cf[3]);
            *(s16x4*)((char*)rad_lds + byte) = pk;
        }
        __syncthreads();

        // ---- P2: U (per-edge) then final accumulate ----
#pragma unroll
        for (int ei = 0; ei < 2; ei++) {
            int e = wave * 2 + ei;
            // B of U mfma: basT[e][s=l15][i = kg*8..+8] (kg>=2 reads zero pad)
            int bbyte = (e * SD + l15) * 80 + kg * 16;
            bbyte ^= ((((e & 1) << 1) | (l15 >> 3)) << 4);
            s16x8 bb = *(const s16x8*)((char*)basT + bbyte);
#pragma unroll
            for (int ch = 0; ch < 2; ch++) {
                fx4 u = __builtin_amdgcn_mfma_f32_16x16x32_bf16(feats[ei][ch], bb, zz, 0, 0, 0);
                int c_w = ch * 16 + (kg << 2);
                int ubyte = (e * SD + l15) * 80 + c_w * 2;
                s16x4 pk;
                pk[0] = (short)f2b(u[0]); pk[1] = (short)f2b(u[1]);
                pk[2] = (short)f2b(u[2]); pk[3] = (short)f2b(u[3]);
                *(s16x4*)((char*)U_lds + ubyte) = pk;
            }
            // B of final mfma: U_lds[e][s=l15][c = kg*8..+8] (same wave wrote it)
            int ubyte2 = (e * SD + l15) * 80 + kg * 16;
            s16x8 ub = *(const s16x8*)((char*)U_lds + ubyte2);
#pragma unroll
            for (int oh = 0; oh < 2; oh++) {
                int o = oh * 16 + l15;
                int abyte = e * 2048 + o * 64 + kg * 16;
                abyte ^= (((e ^ o) & 7) << 4);
                s16x8 ra = *(const s16x8*)((char*)rad_lds + abyte);
                acc[ei * 2 + oh] =
                    __builtin_amdgcn_mfma_f32_16x16x32_bf16(ra, ub, acc[ei * 2 + oh], 0, 0, 0);
            }
        }
        __syncthreads();
    }

    // ---- epilogue: atomic segment-sum into out[dst][o][s] ----
#pragma unroll
    for (int ei = 0; ei < 2; ei++) {
        int e = wave * 2 + ei;
        int d = dst[eb + e];
        float* op = &out[(size_t)d * (CC * SD)];
#pragma unroll
        for (int oh = 0; oh < 2; oh++) {
            fx4 a = acc[ei * 2 + oh];
#pragma unroll
            for (int r = 0; r < 4; r++) {
                int o = oh * 16 + (kg << 2) + r;
                atomicAdd(&op[o * SD + l15], a[r]);
            }
        }
    }
}

// ---------------- K3: self-interaction out[n][o][s] += deg[n]*sum_c ks[o][c]*nf[n][c][j] ----
__global__ __launch_bounds__(256) void k_self(
    const float* __restrict__ nf0, const float* __restrict__ nf1,
    const float* __restrict__ nf2, const float* __restrict__ nf3,
    const float* __restrict__ ks0, const float* __restrict__ ks1,
    const float* __restrict__ ks2, const float* __restrict__ ks3,
    const int* __restrict__ deg, float* __restrict__ out) {
    int idx = blockIdx.x * 256 + threadIdx.x;   // over N*32*16 = 524288
    if (idx >= NN * CC * SD) return;
    int n = idx >> 9;
    int rem = idx & 511;
    int o = rem >> 4;
    int s = rem & 15;
    const float* nf;
    const float* ks;
    int dim, off;
    if (s < 1) { nf = nf0; ks = ks0; dim = 1; off = 0; }
    else if (s < 4) { nf = nf1; ks = ks1; dim = 3; off = 1; }
    else if (s < 9) { nf = nf2; ks = ks2; dim = 5; off = 4; }
    else { nf = nf3; ks = ks3; dim = 7; off = 9; }
    int j = s - off;
    float acc = 0.f;
#pragma unroll
    for (int c = 0; c < CC; c++) acc += ks[o * CC + c] * nf[(n * CC + c) * dim + j];
    out[idx] += (float)deg[n] * acc;
}

extern "C" void kernel_launch(void* const* d_in, const int* in_sizes, int n_in,
                              void* d_out, int out_size, void* d_ws, size_t ws_size,
                              hipStream_t stream) {
    const float* nf0 = (const float*)d_in[0];
    const float* nf1 = (const float*)d_in[1];
    const float* nf2 = (const float*)d_in[2];
    const float* nf3 = (const float*)d_in[3];
    const float* ef = (const float*)d_in[4];
    const float* basis = (const float*)d_in[5];
    const int* src = (const int*)d_in[6];
    const int* dst = (const int*)d_in[7];
    const float* w1 = (const float*)d_in[8];
    const float* b1 = (const float*)d_in[9];
    const float* w2 = (const float*)d_in[10];
    const float* b2 = (const float*)d_in[11];
    const float* w3 = (const float*)d_in[12];
    const float* ks0 = (const float*)d_in[13];
    const float* ks1 = (const float*)d_in[14];
    const float* ks2 = (const float*)d_in[15];
    const float* ks3 = (const float*)d_in[16];
    float* out = (float*)d_out;

    // workspace layout
    unsigned short* h2 = (unsigned short*)d_ws;                    // 4096*32*2 = 256 KB
    int* deg = (int*)((char*)d_ws + EE * MIDC * 2);                // 4 KB
    unsigned short* w3t2 = (unsigned short*)((char*)d_ws + EE * MIDC * 2 + 4096);  // 2.88 MB

    hipMemsetAsync(d_out, 0, (size_t)out_size * sizeof(float), stream);
    hipMemsetAsync(deg, 0, NN * sizeof(int), stream);

    k_w3t2<<<128, 256, 0, stream>>>(w3, w3t2);
    k_h<<<EE / 256, 256, 0, stream>>>(ef, w1, b1, w2, b2, dst, h2, deg);
    k_main<<<512, 512, 0, stream>>>(nf0, nf1, nf2, nf3, basis, src, dst, h2, w3t2, out);
    k_self<<<(NN * CC * SD) / 256, 256, 0, stream>>>(nf0, nf1, nf2, nf3, ks0, ks1,
                                                     ks2, ks3, deg, out);
}